// Round 9
// baseline (440.483 us; speedup 1.0000x reference)
//
#include <hip/hip_runtime.h>
#include <math.h>

constexpr int N_ROWS = 1024;
constexpr int DDIM   = 512;
constexpr int C_CLS  = 100000;
constexpr float MARG = 0.4f;
constexpr int NT8    = 784;                 // class tiles (BN=128) main path
constexpr int WPAD8  = 100352;              // 784*128
constexpr int NT_FB  = 782;                 // fallback class tiles (BN=128, bf16 path)

typedef __attribute__((ext_vector_type(8))) short bf16x8;
typedef __attribute__((ext_vector_type(4))) float f32x4;
typedef __attribute__((ext_vector_type(4))) int   i32x4;
typedef __attribute__((ext_vector_type(8))) int   i32x8;
typedef __attribute__((address_space(1))) const void gvoid_t;
typedef __attribute__((address_space(3))) void lvoid_t;

__device__ __forceinline__ unsigned int f2bf(float x) {
    union { float f; unsigned int u; } v; v.f = x;
    return (v.u + 0x7FFFu + ((v.u >> 16) & 1u)) >> 16;   // RNE to bf16 bits
}

__device__ __forceinline__ float wave_sum(float s) {
    #pragma unroll
    for (int m = 1; m < 64; m <<= 1) s += __shfl_xor(s, m, 64);
    return s;
}

// ---- f32 -> e4m3fn ----
#if __has_builtin(__builtin_amdgcn_cvt_pk_fp8_f32)
__device__ __forceinline__ unsigned int pk4_e4m3(float a, float b, float c, float d) {
    unsigned int u = (unsigned int)__builtin_amdgcn_cvt_pk_fp8_f32(a, b, 0, false);
    u = (unsigned int)__builtin_amdgcn_cvt_pk_fp8_f32(c, d, (int)u, true);
    return u;
}
#else
__device__ __forceinline__ unsigned int sw_e4m3(float x) {
    x = fminf(fmaxf(x, -448.f), 448.f);
    unsigned int s = (x < 0.f) ? 0x80u : 0u;
    float ax = fabsf(x);
    if (ax < 7.8125e-3f) {
        int q = (int)rintf(ax * 512.f);
        if (q >= 8) return s | 0x08;
        return s | (unsigned int)q;
    }
    int e; float m = frexpf(ax, &e);
    int q = (int)rintf(m * 16.f);
    if (q == 16) { q = 8; e += 1; }
    int E = e - 1 + 7;
    if (E > 15) { E = 15; q = 14; }
    return s | ((unsigned int)E << 3) | (unsigned int)(q - 8);
}
__device__ __forceinline__ unsigned int pk4_e4m3(float a, float b, float c, float d) {
    return sw_e4m3(a) | (sw_e4m3(b) << 8) | (sw_e4m3(c) << 16) | (sw_e4m3(d) << 24);
}
#endif

// ---- e4m3fn -> f32 (manual, no-NaN inputs) ----
__device__ __forceinline__ float dec_e4m3(unsigned int b) {
    const unsigned int E = (b >> 3) & 15u, M = b & 7u;
    if (E) {
        union { unsigned int u; float f; } v;
        v.u = ((b & 0x80u) << 24) | ((E + 120u) << 23) | (M << 20);
        return v.f;
    }
    float d = (float)M * 0.001953125f;
    return (b & 0x80u) ? -d : d;
}

// ---- per-row norm of embs -> g[i], normalized fp8 ehat8 ----
__global__ __launch_bounds__(256) void prep_embs8(const float* __restrict__ embs,
                                                  float* __restrict__ g,
                                                  unsigned char* __restrict__ ehat8) {
    const int row  = blockIdx.x * 4 + (threadIdx.x >> 6);
    const int lane = threadIdx.x & 63;
    const float4* src = (const float4*)(embs + (size_t)row * DDIM + lane * 8);
    const float4 a = src[0], b = src[1];
    float ss = a.x*a.x + a.y*a.y + a.z*a.z + a.w*a.w
             + b.x*b.x + b.y*b.y + b.z*b.z + b.w*b.w;
    ss = wave_sum(ss);
    const float norm = sqrtf(ss);
    const float rn = 1.f / norm;
    if (lane == 0) {
        float gg = (norm - 20.f) / sqrtf(10000.f + 1e-3f) * 0.333f;
        gg = fminf(fmaxf(gg, -1.f), 1.f);
        g[row] = gg;
    }
    uint2 pk;
    pk.x = pk4_e4m3(a.x*rn, a.y*rn, a.z*rn, a.w*rn);
    pk.y = pk4_e4m3(b.x*rn, b.y*rn, b.z*rn, b.w*rn);
    *(uint2*)(ehat8 + (size_t)row * DDIM + lane * 8) = pk;
}

// ---- normalized fp8 weight; rows >= C_CLS zeroed ----
__global__ __launch_bounds__(256) void prep_what8(const float* __restrict__ w,
                                                  unsigned char* __restrict__ what8) {
    const int row  = blockIdx.x * 4 + (threadIdx.x >> 6);
    const int lane = threadIdx.x & 63;
    if (row >= C_CLS) {
        *(uint2*)(what8 + (size_t)row * DDIM + lane * 8) = make_uint2(0u, 0u);
        return;
    }
    const float4* src = (const float4*)(w + (size_t)row * DDIM + lane * 8);
    const float4 a = src[0], b = src[1];
    float ss = a.x*a.x + a.y*a.y + a.z*a.z + a.w*a.w
             + b.x*b.x + b.y*b.y + b.z*b.z + b.w*b.w;
    ss = wave_sum(ss);
    const float rn = rsqrtf(ss);
    uint2 pk;
    pk.x = pk4_e4m3(a.x*rn, a.y*rn, a.z*rn, a.w*rn);
    pk.y = pk4_e4m3(b.x*rn, b.y*rn, b.z*rn, b.w*rn);
    *(uint2*)(what8 + (size_t)row * DDIM + lane * 8) = pk;
}

__device__ __forceinline__ i32x8 join8(i32x4 lo, i32x4 hi) {
    return __builtin_shufflevector(lo, hi, 0, 1, 2, 3, 4, 5, 6, 7);
}

// ==== 128x128 / BK=128 fp8 GEMM, slab-linear LDS, single-buffer, 3 blocks/CU ====
// LDS layout (fragment-major, conflict-free, verified r8: SQ_LDS_BANK_CONFLICT=0):
//   slab sl (0..7) = rows/cols 16*sl..16*sl+15; lane l's 32 B of the fragment live
//   at sl*2048 + l*32 (two 16B halves). gload_lds slot s = 2*l + half.
// No intra-block pipelining: stage -> syncthreads -> compute -> syncthreads.
// Latency hiding comes from 3 independent blocks/CU (12 waves) at staggered phases.
__global__ __launch_bounds__(256, 3) void gemm_s1(
        const unsigned char* __restrict__ ehat8,   // [1024][512] e4m3
        const unsigned char* __restrict__ what8,   // [WPAD8][512] e4m3, pad rows zero
        float* __restrict__ psum)                  // [1024][NT8] partial exp-sums
{
    __shared__ __align__(16) unsigned char Ab[16384];     // 16 KB (one K-tile of A)
    __shared__ __align__(16) unsigned char Bb[16384];     // 16 KB (one K-tile of B)
    __shared__ float redbuf[2][128];                      // 1 KB

    const int tid  = threadIdx.x;
    const int lane = tid & 63;
    const int wv   = tid >> 6;
    const int wr   = wv >> 1;     // 0..1 : 64-row half
    const int wc   = wv & 1;      // 0..1 : 64-col half
    const int r    = lane & 15;
    const int q    = lane >> 4;

    // XCD swizzle: grid 6272 = 8*784; 8 row-tiles of one B panel on one XCD
    const int wgid   = ((int)blockIdx.x & 7) * 784 + ((int)blockIdx.x >> 3);
    const int tile_c = wgid >> 3;
    const int tile_r = wgid & 7;
    const int row0   = tile_r * 128;
    const int col0   = tile_c * 128;

    // staging map: wave wv owns slabs {2wv, 2wv+1} of A and of B; 2 issues/slab.
    // issue i fills slots s = i*64+lane: reader-lane l = s>>1, half hb = s&1
    //   -> grow = 16*sl + (l&15), kbytes = (l>>4)*32 + hb*16  (+ t*128)
    const int l0   = lane >> 1;
    const int rowi = l0 & 15;
    const int kb0  = (l0 >> 4) * 32 + (lane & 1) * 16;    // issue 0; issue 1 = +64

    f32x4 acc[4][4];
    #pragma unroll
    for (int m = 0; m < 4; ++m)
        #pragma unroll
        for (int n = 0; n < 4; ++n) acc[m][n] = f32x4{0.f, 0.f, 0.f, 0.f};

    const int t0 = (int)blockIdx.x & 3;   // stagger K order across co-resident blocks

    for (int it = 0; it < 4; ++it) {
        const int t = (t0 + it) & 3;
        // ---- stage K-tile t (8 gload_lds issues per wave) ----
        #pragma unroll
        for (int ss = 0; ss < 2; ++ss) {
            const int sl = wv * 2 + ss;
            const unsigned char* ga = ehat8 + (size_t)(row0 + 16 * sl + rowi) * DDIM
                                      + t * 128 + kb0;
            __builtin_amdgcn_global_load_lds((gvoid_t*)ga,       (lvoid_t*)(Ab + sl * 2048),        16, 0, 0);
            __builtin_amdgcn_global_load_lds((gvoid_t*)(ga + 64),(lvoid_t*)(Ab + sl * 2048 + 1024), 16, 0, 0);
            const unsigned char* gb = what8 + (size_t)(col0 + 16 * sl + rowi) * DDIM
                                      + t * 128 + kb0;
            __builtin_amdgcn_global_load_lds((gvoid_t*)gb,       (lvoid_t*)(Bb + sl * 2048),        16, 0, 0);
            __builtin_amdgcn_global_load_lds((gvoid_t*)(gb + 64),(lvoid_t*)(Bb + sl * 2048 + 1024), 16, 0, 0);
        }
        __syncthreads();                  // drains vmcnt(0) + barrier (single buffer)

        // ---- compute: all addresses are base + compile-time offsets ----
        i32x4 bR[4][2];
        #pragma unroll
        for (int n = 0; n < 4; ++n) {
            bR[n][0] = *(const i32x4*)(Bb + (wc * 4 + n) * 2048 + lane * 32);
            bR[n][1] = *(const i32x4*)(Bb + (wc * 4 + n) * 2048 + lane * 32 + 16);
        }
        __builtin_amdgcn_s_setprio(1);
        #pragma unroll
        for (int m = 0; m < 4; ++m) {
            const i32x4 a0 = *(const i32x4*)(Ab + (wr * 4 + m) * 2048 + lane * 32);
            const i32x4 a1 = *(const i32x4*)(Ab + (wr * 4 + m) * 2048 + lane * 32 + 16);
            const i32x8 av = join8(a0, a1);
            #pragma unroll
            for (int n = 0; n < 4; ++n)
                acc[m][n] = __builtin_amdgcn_mfma_scale_f32_16x16x128_f8f6f4(
                                av, join8(bR[n][0], bR[n][1]), acc[m][n], 0, 0, 0, 127, 0, 127);
        }
        __builtin_amdgcn_s_setprio(0);
        __syncthreads();                  // all reads of tile t retired before restage
    }

    // ---- epilogue: clamp + exp-sum (pad cols contribute e^-64 ~ 0) ----
    #pragma unroll
    for (int m = 0; m < 4; ++m) {
        #pragma unroll
        for (int j = 0; j < 4; ++j) {
            const int lrow = wr * 64 + m * 16 + q * 4 + j;
            float s = 0.f;
            #pragma unroll
            for (int n = 0; n < 4; ++n) {
                float v = acc[m][n][j];
                v = fminf(fmaxf(v, -0.999f), 0.999f);
                s += __expf(64.f * v - 64.f);
            }
            #pragma unroll
            for (int msk = 1; msk < 16; msk <<= 1) s += __shfl_xor(s, msk, 64);
            if (r == 0) redbuf[wc][lrow] = s;
        }
    }
    __syncthreads();
    for (int t = tid; t < 128; t += 256)
        psum[(size_t)(row0 + t) * NT8 + tile_c] = redbuf[0][t] + redbuf[1][t];
}

// ---- per-row combine: float partials + recomputed fp8 label dot + margins ----
__global__ __launch_bounds__(256) void reduce_rows8(
        const float* __restrict__ psum,            // [1024][NT8]
        const unsigned char* __restrict__ ehat8,
        const unsigned char* __restrict__ what8,
        const int* __restrict__ labels,
        const float* __restrict__ g,
        float* __restrict__ losses) {
    const int row  = blockIdx.x * 4 + (threadIdx.x >> 6);
    const int lane = threadIdx.x & 63;
    const float* p = psum + (size_t)row * NT8;
    float s = 0.f;
    for (int t = lane; t < NT8; t += 64) s += p[t];
    const int lab = labels[row];
    const uint2 ea = *(const uint2*)(ehat8 + (size_t)row * DDIM + lane * 8);
    const uint2 wa = *(const uint2*)(what8 + (size_t)lab * DDIM + lane * 8);
    float d = 0.f;
    #pragma unroll
    for (int i = 0; i < 4; ++i)
        d += dec_e4m3((ea.x >> (8 * i)) & 0xFFu) * dec_e4m3((wa.x >> (8 * i)) & 0xFFu);
    #pragma unroll
    for (int i = 0; i < 4; ++i)
        d += dec_e4m3((ea.y >> (8 * i)) & 0xFFu) * dec_e4m3((wa.y >> (8 * i)) & 0xFFu);
    s = wave_sum(s);
    d = wave_sum(d);
    if (lane == 0) {
        const float v  = fminf(fmaxf(d, -0.999f), 0.999f);
        const float gg = g[row];
        float th = acosf(v) - MARG * gg;
        th = fminf(fmaxf(th, 0.f), 3.14159265358979323846f);
        const float vm = cosf(th) - (1.f + MARG) * gg;
        s = s - __expf(64.f * v - 64.f) + __expf(64.f * vm - 64.f);
        losses[row] = 64.f + logf(s) - 64.f * vm;
    }
}

// ==== fallback path (bf16, round-1 verified) ====
__global__ __launch_bounds__(256) void prep_embs(const float* __restrict__ embs,
                                                 float* __restrict__ g,
                                                 unsigned short* __restrict__ ehat) {
    const int row  = blockIdx.x * 4 + (threadIdx.x >> 6);
    const int lane = threadIdx.x & 63;
    const float4* src = (const float4*)(embs + (size_t)row * DDIM + lane * 8);
    const float4 a = src[0], b = src[1];
    float ss = a.x*a.x + a.y*a.y + a.z*a.z + a.w*a.w
             + b.x*b.x + b.y*b.y + b.z*b.z + b.w*b.w;
    ss = wave_sum(ss);
    const float norm = sqrtf(ss);
    const float rn = 1.f / norm;
    if (lane == 0) {
        float gg = (norm - 20.f) / sqrtf(10000.f + 1e-3f) * 0.333f;
        gg = fminf(fmaxf(gg, -1.f), 1.f);
        g[row] = gg;
    }
    uint4 pk;
    pk.x = f2bf(a.x*rn) | (f2bf(a.y*rn) << 16);
    pk.y = f2bf(a.z*rn) | (f2bf(a.w*rn) << 16);
    pk.z = f2bf(b.x*rn) | (f2bf(b.y*rn) << 16);
    pk.w = f2bf(b.z*rn) | (f2bf(b.w*rn) << 16);
    *(uint4*)(ehat + (size_t)row * DDIM + lane * 8) = pk;
}

__global__ __launch_bounds__(256) void prep_wnorm(const float* __restrict__ w,
                                                  float* __restrict__ rnormw) {
    const int row  = blockIdx.x * 4 + (threadIdx.x >> 6);
    const int lane = threadIdx.x & 63;
    const float4* src = (const float4*)(w + (size_t)row * DDIM + lane * 8);
    const float4 a = src[0], b = src[1];
    float ss = a.x*a.x + a.y*a.y + a.z*a.z + a.w*a.w
             + b.x*b.x + b.y*b.y + b.z*b.z + b.w*b.w;
    ss = wave_sum(ss);
    if (lane == 0) rnormw[row] = 1.f / sqrtf(ss);
}

__global__ __launch_bounds__(256, 2) void gemm_fused_fb(
        const unsigned short* __restrict__ ehat,
        const float* __restrict__ weight,
        const float* __restrict__ rnormw,
        const int* __restrict__ labels,
        float* __restrict__ psum,
        float* __restrict__ dlab)
{
    constexpr int BM = 128, BN = 128, BK = 32;
    __shared__ __align__(16) unsigned short Asf[BM * BK];
    __shared__ __align__(16) unsigned short Bsf[BN * BK];
    __shared__ float redbuf[2][BM];

    const int bid    = blockIdx.x;
    const int tile_c = bid >> 3;
    const int tile_r = bid & 7;
    const int row0   = tile_r * BM;
    const int col0   = tile_c * BN;

    const int tid  = threadIdx.x;
    const int lane = tid & 63;
    const int wv   = tid >> 6;
    const int wr   = wv >> 1;
    const int wc   = wv & 1;

    f32x4 acc[4][4];
    #pragma unroll
    for (int m = 0; m < 4; ++m)
        #pragma unroll
        for (int n = 0; n < 4; ++n) acc[m][n] = f32x4{0.f, 0.f, 0.f, 0.f};

    const int kq    = tid & 7;
    const int brow0 = tid >> 3;
    int   cidx[4];
    float rnv[4];
    #pragma unroll
    for (int p = 0; p < 4; ++p) {
        int c = col0 + p * 32 + brow0;
        c = c < C_CLS ? c : C_CLS - 1;
        cidx[p] = c;
        rnv[p]  = rnormw[c];
    }

    for (int kt = 0; kt < DDIM / BK; ++kt) {
        const int kbase = kt * BK;
        #pragma unroll
        for (int call = 0; call < 2; ++call) {
            const int chunk = call * 256 + tid;
            const uint4 dd = *(const uint4*)(ehat + (size_t)(row0 + (chunk >> 2)) * DDIM
                                             + kbase + (chunk & 3) * 8);
            *(uint4*)(Asf + chunk * 8) = dd;
        }
        #pragma unroll
        for (int p = 0; p < 4; ++p) {
            const float4 wd = *(const float4*)(weight + (size_t)cidx[p] * DDIM + kbase + kq * 4);
            const float rr = rnv[p];
            const unsigned int lo = f2bf(wd.x * rr) | (f2bf(wd.y * rr) << 16);
            const unsigned int hi = f2bf(wd.z * rr) | (f2bf(wd.w * rr) << 16);
            *(uint2*)(Bsf + (p * 32 + brow0) * BK + kq * 4) = make_uint2(lo, hi);
        }
        __syncthreads();
        bf16x8 af[4], bfr[4];
        const int lr  = lane & 15;
        const int lko = (lane >> 4) * 8;
        #pragma unroll
        for (int m = 0; m < 4; ++m)
            af[m] = *(const bf16x8*)(Asf + (wr * 64 + m * 16 + lr) * BK + lko);
        #pragma unroll
        for (int n = 0; n < 4; ++n)
            bfr[n] = *(const bf16x8*)(Bsf + (wc * 64 + n * 16 + lr) * BK + lko);
        #pragma unroll
        for (int m = 0; m < 4; ++m)
            #pragma unroll
            for (int n = 0; n < 4; ++n)
                acc[m][n] = __builtin_amdgcn_mfma_f32_16x16x32_bf16(af[m], bfr[n], acc[m][n], 0, 0, 0);
        __syncthreads();
    }

    #pragma unroll
    for (int m = 0; m < 4; ++m) {
        #pragma unroll
        for (int j = 0; j < 4; ++j) {
            const int lrow  = wr * 64 + m * 16 + ((lane >> 4) << 2) + j;
            const int r_abs = row0 + lrow;
            const int lab   = labels[r_abs];
            float s = 0.f;
            #pragma unroll
            for (int n = 0; n < 4; ++n) {
                const int c_abs = col0 + wc * 64 + n * 16 + (lane & 15);
                float v = acc[m][n][j];
                v = fminf(fmaxf(v, -0.999f), 0.999f);
                if (c_abs == lab) dlab[r_abs] = v;
                if (c_abs < C_CLS) s += __expf(64.f * v - 64.f);
            }
            #pragma unroll
            for (int msk = 1; msk < 16; msk <<= 1) s += __shfl_xor(s, msk, 64);
            if ((lane & 15) == 0) redbuf[wc][lrow] = s;
        }
    }
    __syncthreads();
    for (int t = tid; t < BM; t += 256)
        psum[(size_t)(row0 + t) * NT_FB + tile_c] = redbuf[0][t] + redbuf[1][t];
}

__global__ __launch_bounds__(256) void reduce_rows(const float* __restrict__ psum,
                                                   const float* __restrict__ dlab,
                                                   const float* __restrict__ g,
                                                   float* __restrict__ losses, int nt) {
    const int row  = blockIdx.x * 4 + (threadIdx.x >> 6);
    const int lane = threadIdx.x & 63;
    const float* p = psum + (size_t)row * nt;
    float s = 0.f;
    for (int t = lane; t < nt; t += 64) s += p[t];
    s = wave_sum(s);
    if (lane == 0) {
        const float v  = dlab[row];
        const float gg = g[row];
        float th = acosf(v) - MARG * gg;
        th = fminf(fmaxf(th, 0.f), 3.14159265358979323846f);
        const float vm = cosf(th) - (1.f + MARG) * gg;
        s = s - __expf(64.f * v - 64.f) + __expf(64.f * vm - 64.f);
        losses[row] = 64.f + logf(s) - 64.f * vm;
    }
}

__global__ __launch_bounds__(256) void final_mean(const float* __restrict__ losses,
                                                  float* __restrict__ out) {
    const int tid = threadIdx.x;
    float s = 0.f;
    #pragma unroll
    for (int i = 0; i < 4; ++i) s += losses[tid + i * 256];
    s = wave_sum(s);
    __shared__ float red[4];
    if ((tid & 63) == 0) red[tid >> 6] = s;
    __syncthreads();
    if (tid == 0) out[0] = (red[0] + red[1] + red[2] + red[3]) * (1.f / 1024.f);
}

extern "C" void kernel_launch(void* const* d_in, const int* in_sizes, int n_in,
                              void* d_out, int out_size, void* d_ws, size_t ws_size,
                              hipStream_t stream) {
    const float* embs   = (const float*)d_in[0];
    const float* weight = (const float*)d_in[1];
    const int*   labels = (const int*)d_in[2];
    float* out = (float*)d_out;
    unsigned char* wsb = (unsigned char*)d_ws;

    // main-path layout (bytes): what8 | ehat8 | psum(float) | g | losses
    const size_t WHAT8_B = (size_t)WPAD8 * DDIM;          // 51,380,224
    const size_t EHAT8_B = (size_t)N_ROWS * DDIM;         // 524,288
    const size_t PSUM_B  = (size_t)N_ROWS * NT8 * 4;      // 3,211,264
    const size_t NEED_B  = WHAT8_B + EHAT8_B + PSUM_B + 2 * 4096;

    if (ws_size >= NEED_B) {
        unsigned char* what8 = wsb;
        unsigned char* ehat8 = wsb + WHAT8_B;
        float* psum   = (float*)(wsb + WHAT8_B + EHAT8_B);
        float* gbuf   = psum + (size_t)N_ROWS * NT8;
        float* losses = gbuf + 1024;

        prep_embs8<<<N_ROWS / 4, 256, 0, stream>>>(embs, gbuf, ehat8);
        prep_what8<<<WPAD8 / 4, 256, 0, stream>>>(weight, what8);
        gemm_s1<<<NT8 * 8, 256, 0, stream>>>(ehat8, what8, psum);
        reduce_rows8<<<N_ROWS / 4, 256, 0, stream>>>(psum, ehat8, what8, labels, gbuf, losses);
        final_mean<<<1, 256, 0, stream>>>(losses, out);
    } else {
        float* ws = (float*)d_ws;
        float* rnormw = ws + 0;
        float* gbuf   = ws + 100352;
        float* dlab   = ws + 101376;
        float* losses = ws + 102400;
        unsigned short* ehat = (unsigned short*)(ws + 103424);
        float* psum   = ws + 103424 + 262144;

        prep_embs <<<N_ROWS / 4, 256, 0, stream>>>(embs, gbuf, ehat);
        prep_wnorm<<<C_CLS / 4, 256, 0, stream>>>(weight, rnormw);
        gemm_fused_fb<<<NT_FB * 8, 256, 0, stream>>>(ehat, weight, rnormw, labels, psum, dlab);
        reduce_rows<<<N_ROWS / 4, 256, 0, stream>>>(psum, dlab, gbuf, losses, NT_FB);
        final_mean<<<1, 256, 0, stream>>>(losses, out);
    }
}

// Round 10
// 183.803 us; speedup vs baseline: 2.3965x; 2.3965x over previous
//
#include <hip/hip_runtime.h>
#include <math.h>

constexpr int N_ROWS = 1024;
constexpr int DDIM   = 512;
constexpr int C_CLS  = 100000;
constexpr float MARG = 0.4f;
constexpr int NT8    = 784;                 // class tiles (BN=128) main path
constexpr int WPAD8  = 100352;              // 784*128
constexpr int NT_FB  = 782;                 // fallback class tiles (BN=128, bf16 path)

typedef __attribute__((ext_vector_type(8))) short bf16x8;
typedef __attribute__((ext_vector_type(4))) float f32x4;
typedef __attribute__((ext_vector_type(4))) int   i32x4;
typedef __attribute__((ext_vector_type(8))) int   i32x8;
typedef __attribute__((address_space(1))) const void gvoid_t;
typedef __attribute__((address_space(3))) void lvoid_t;

__device__ __forceinline__ unsigned int f2bf(float x) {
    union { float f; unsigned int u; } v; v.f = x;
    return (v.u + 0x7FFFu + ((v.u >> 16) & 1u)) >> 16;   // RNE to bf16 bits
}

__device__ __forceinline__ float wave_sum(float s) {
    #pragma unroll
    for (int m = 1; m < 64; m <<= 1) s += __shfl_xor(s, m, 64);
    return s;
}

// ---- f32 -> e4m3fn ----
#if __has_builtin(__builtin_amdgcn_cvt_pk_fp8_f32)
__device__ __forceinline__ unsigned int pk4_e4m3(float a, float b, float c, float d) {
    unsigned int u = (unsigned int)__builtin_amdgcn_cvt_pk_fp8_f32(a, b, 0, false);
    u = (unsigned int)__builtin_amdgcn_cvt_pk_fp8_f32(c, d, (int)u, true);
    return u;
}
#else
__device__ __forceinline__ unsigned int sw_e4m3(float x) {
    x = fminf(fmaxf(x, -448.f), 448.f);
    unsigned int s = (x < 0.f) ? 0x80u : 0u;
    float ax = fabsf(x);
    if (ax < 7.8125e-3f) {
        int q = (int)rintf(ax * 512.f);
        if (q >= 8) return s | 0x08;
        return s | (unsigned int)q;
    }
    int e; float m = frexpf(ax, &e);
    int q = (int)rintf(m * 16.f);
    if (q == 16) { q = 8; e += 1; }
    int E = e - 1 + 7;
    if (E > 15) { E = 15; q = 14; }
    return s | ((unsigned int)E << 3) | (unsigned int)(q - 8);
}
__device__ __forceinline__ unsigned int pk4_e4m3(float a, float b, float c, float d) {
    return sw_e4m3(a) | (sw_e4m3(b) << 8) | (sw_e4m3(c) << 16) | (sw_e4m3(d) << 24);
}
#endif

// ---- e4m3fn -> f32 (manual, no-NaN inputs) ----
__device__ __forceinline__ float dec_e4m3(unsigned int b) {
    const unsigned int E = (b >> 3) & 15u, M = b & 7u;
    if (E) {
        union { unsigned int u; float f; } v;
        v.u = ((b & 0x80u) << 24) | ((E + 120u) << 23) | (M << 20);
        return v.f;
    }
    float d = (float)M * 0.001953125f;
    return (b & 0x80u) ? -d : d;
}

// ---- per-row norm of embs -> g[i], normalized fp8 ehat8 ----
__global__ __launch_bounds__(256) void prep_embs8(const float* __restrict__ embs,
                                                  float* __restrict__ g,
                                                  unsigned char* __restrict__ ehat8) {
    const int row  = blockIdx.x * 4 + (threadIdx.x >> 6);
    const int lane = threadIdx.x & 63;
    const float4* src = (const float4*)(embs + (size_t)row * DDIM + lane * 8);
    const float4 a = src[0], b = src[1];
    float ss = a.x*a.x + a.y*a.y + a.z*a.z + a.w*a.w
             + b.x*b.x + b.y*b.y + b.z*b.z + b.w*b.w;
    ss = wave_sum(ss);
    const float norm = sqrtf(ss);
    const float rn = 1.f / norm;
    if (lane == 0) {
        float gg = (norm - 20.f) / sqrtf(10000.f + 1e-3f) * 0.333f;
        gg = fminf(fmaxf(gg, -1.f), 1.f);
        g[row] = gg;
    }
    uint2 pk;
    pk.x = pk4_e4m3(a.x*rn, a.y*rn, a.z*rn, a.w*rn);
    pk.y = pk4_e4m3(b.x*rn, b.y*rn, b.z*rn, b.w*rn);
    *(uint2*)(ehat8 + (size_t)row * DDIM + lane * 8) = pk;
}

// ---- normalized fp8 weight; rows >= C_CLS zeroed ----
__global__ __launch_bounds__(256) void prep_what8(const float* __restrict__ w,
                                                  unsigned char* __restrict__ what8) {
    const int row  = blockIdx.x * 4 + (threadIdx.x >> 6);
    const int lane = threadIdx.x & 63;
    if (row >= C_CLS) {
        *(uint2*)(what8 + (size_t)row * DDIM + lane * 8) = make_uint2(0u, 0u);
        return;
    }
    const float4* src = (const float4*)(w + (size_t)row * DDIM + lane * 8);
    const float4 a = src[0], b = src[1];
    float ss = a.x*a.x + a.y*a.y + a.z*a.z + a.w*a.w
             + b.x*b.x + b.y*b.y + b.z*b.z + b.w*b.w;
    ss = wave_sum(ss);
    const float rn = rsqrtf(ss);
    uint2 pk;
    pk.x = pk4_e4m3(a.x*rn, a.y*rn, a.z*rn, a.w*rn);
    pk.y = pk4_e4m3(b.x*rn, b.y*rn, b.z*rn, b.w*rn);
    *(uint2*)(what8 + (size_t)row * DDIM + lane * 8) = pk;
}

__device__ __forceinline__ i32x8 join8(i32x4 lo, i32x4 hi) {
    return __builtin_shufflevector(lo, hi, 0, 1, 2, 3, 4, 5, 6, 7);
}

// ==== 128x128 / BK=128 fp8 GEMM, single-buffer, 4 blocks/CU ====
// LDS layout (r8-verified conflict-free, SQ_LDS_BANK_CONFLICT=0):
//   fragment slab sl (16 rows) = 2 KB: half h at sl*2048 + h*1024, lane l's
//   16B at + l*16 (contiguous per wave -> 0 conflicts). Staging issue (sl,h):
//   lane l sources row 16*sl + (l&15), kbyte = t*128 + (l>>4)*32 + h*16.
// Latency hiding: 4 independent blocks/CU at staggered K-phases (no intra-
// block pipelining; __syncthreads drains vmcnt(0) between stage and compute).
__global__ __launch_bounds__(256, 2) void gemm_s1(
        const unsigned char* __restrict__ ehat8,   // [1024][512] e4m3
        const unsigned char* __restrict__ what8,   // [WPAD8][512] e4m3, pad rows zero
        float* __restrict__ psum)                  // [1024][NT8] partial exp-sums
{
    __shared__ __align__(16) unsigned char Ab[16384];     // 16 KB (one K-tile of A)
    __shared__ __align__(16) unsigned char Bb[16384];     // 16 KB (one K-tile of B)
    __shared__ float redbuf[2][128];                      // 1 KB

    const int tid  = threadIdx.x;
    const int lane = tid & 63;
    const int wv   = tid >> 6;
    const int wr   = wv >> 1;     // 0..1 : 64-row half
    const int wc   = wv & 1;      // 0..1 : 64-col half
    const int r    = lane & 15;
    const int q    = lane >> 4;

    // XCD swizzle: grid 6272 = 8*784; 8 row-tiles of one B panel on one XCD
    const int wgid   = ((int)blockIdx.x & 7) * 784 + ((int)blockIdx.x >> 3);
    const int tile_c = wgid >> 3;
    const int tile_r = wgid & 7;
    const int row0   = tile_r * 128;
    const int col0   = tile_c * 128;

    // per-lane staging source base (fragment-order: row r, k-quarter q)
    const unsigned char* Asrc = ehat8 + (size_t)(row0 + r) * DDIM + q * 32;
    const unsigned char* Bsrc = what8 + (size_t)(col0 + r) * DDIM + q * 32;

    f32x4 acc[4][4];
    #pragma unroll
    for (int m = 0; m < 4; ++m)
        #pragma unroll
        for (int n = 0; n < 4; ++n) acc[m][n] = f32x4{0.f, 0.f, 0.f, 0.f};

    const int t0 = (int)blockIdx.x & 3;   // stagger K order across co-resident blocks

    for (int it = 0; it < 4; ++it) {
        const int t = (t0 + it) & 3;
        // ---- stage K-tile t: wave wv fills slabs {2wv, 2wv+1} x halves {0,1} ----
        #pragma unroll
        for (int ss = 0; ss < 2; ++ss) {
            const int sl = wv * 2 + ss;
            const unsigned char* ga = Asrc + (size_t)(16 * sl) * DDIM + t * 128;
            __builtin_amdgcn_global_load_lds((gvoid_t*)ga,        (lvoid_t*)(Ab + sl * 2048),        16, 0, 0);
            __builtin_amdgcn_global_load_lds((gvoid_t*)(ga + 16), (lvoid_t*)(Ab + sl * 2048 + 1024), 16, 0, 0);
            const unsigned char* gb = Bsrc + (size_t)(16 * sl) * DDIM + t * 128;
            __builtin_amdgcn_global_load_lds((gvoid_t*)gb,        (lvoid_t*)(Bb + sl * 2048),        16, 0, 0);
            __builtin_amdgcn_global_load_lds((gvoid_t*)(gb + 16), (lvoid_t*)(Bb + sl * 2048 + 1024), 16, 0, 0);
        }
        __syncthreads();                  // drains vmcnt(0) + barrier (single buffer)

        // ---- compute: contiguous 16B/lane reads, compile-time slab offsets ----
        i32x4 bR[4][2];
        #pragma unroll
        for (int n = 0; n < 4; ++n) {
            bR[n][0] = *(const i32x4*)(Bb + (wc * 4 + n) * 2048 +        lane * 16);
            bR[n][1] = *(const i32x4*)(Bb + (wc * 4 + n) * 2048 + 1024 + lane * 16);
        }
        __builtin_amdgcn_s_setprio(1);
        #pragma unroll
        for (int m = 0; m < 4; ++m) {
            const i32x4 a0 = *(const i32x4*)(Ab + (wr * 4 + m) * 2048 +        lane * 16);
            const i32x4 a1 = *(const i32x4*)(Ab + (wr * 4 + m) * 2048 + 1024 + lane * 16);
            const i32x8 av = join8(a0, a1);
            #pragma unroll
            for (int n = 0; n < 4; ++n)
                acc[m][n] = __builtin_amdgcn_mfma_scale_f32_16x16x128_f8f6f4(
                                av, join8(bR[n][0], bR[n][1]), acc[m][n], 0, 0, 0, 127, 0, 127);
        }
        __builtin_amdgcn_s_setprio(0);
        __syncthreads();                  // all reads of tile t retired before restage
    }

    // ---- epilogue: clamp + exp-sum (pad cols contribute e^-64 ~ 0) ----
    #pragma unroll
    for (int m = 0; m < 4; ++m) {
        #pragma unroll
        for (int j = 0; j < 4; ++j) {
            const int lrow = wr * 64 + m * 16 + q * 4 + j;
            float s = 0.f;
            #pragma unroll
            for (int n = 0; n < 4; ++n) {
                float v = acc[m][n][j];
                v = fminf(fmaxf(v, -0.999f), 0.999f);
                s += __expf(64.f * v - 64.f);
            }
            #pragma unroll
            for (int msk = 1; msk < 16; msk <<= 1) s += __shfl_xor(s, msk, 64);
            if (r == 0) redbuf[wc][lrow] = s;
        }
    }
    __syncthreads();
    for (int t = tid; t < 128; t += 256)
        psum[(size_t)(row0 + t) * NT8 + tile_c] = redbuf[0][t] + redbuf[1][t];
}

// ---- per-row combine: float partials + recomputed fp8 label dot + margins ----
__global__ __launch_bounds__(256) void reduce_rows8(
        const float* __restrict__ psum,            // [1024][NT8]
        const unsigned char* __restrict__ ehat8,
        const unsigned char* __restrict__ what8,
        const int* __restrict__ labels,
        const float* __restrict__ g,
        float* __restrict__ losses) {
    const int row  = blockIdx.x * 4 + (threadIdx.x >> 6);
    const int lane = threadIdx.x & 63;
    const float* p = psum + (size_t)row * NT8;
    float s = 0.f;
    for (int t = lane; t < NT8; t += 64) s += p[t];
    const int lab = labels[row];
    const uint2 ea = *(const uint2*)(ehat8 + (size_t)row * DDIM + lane * 8);
    const uint2 wa = *(const uint2*)(what8 + (size_t)lab * DDIM + lane * 8);
    float d = 0.f;
    #pragma unroll
    for (int i = 0; i < 4; ++i)
        d += dec_e4m3((ea.x >> (8 * i)) & 0xFFu) * dec_e4m3((wa.x >> (8 * i)) & 0xFFu);
    #pragma unroll
    for (int i = 0; i < 4; ++i)
        d += dec_e4m3((ea.y >> (8 * i)) & 0xFFu) * dec_e4m3((wa.y >> (8 * i)) & 0xFFu);
    s = wave_sum(s);
    d = wave_sum(d);
    if (lane == 0) {
        const float v  = fminf(fmaxf(d, -0.999f), 0.999f);
        const float gg = g[row];
        float th = acosf(v) - MARG * gg;
        th = fminf(fmaxf(th, 0.f), 3.14159265358979323846f);
        const float vm = cosf(th) - (1.f + MARG) * gg;
        s = s - __expf(64.f * v - 64.f) + __expf(64.f * vm - 64.f);
        losses[row] = 64.f + logf(s) - 64.f * vm;
    }
}

// ==== fallback path (bf16, round-1 verified) ====
__global__ __launch_bounds__(256) void prep_embs(const float* __restrict__ embs,
                                                 float* __restrict__ g,
                                                 unsigned short* __restrict__ ehat) {
    const int row  = blockIdx.x * 4 + (threadIdx.x >> 6);
    const int lane = threadIdx.x & 63;
    const float4* src = (const float4*)(embs + (size_t)row * DDIM + lane * 8);
    const float4 a = src[0], b = src[1];
    float ss = a.x*a.x + a.y*a.y + a.z*a.z + a.w*a.w
             + b.x*b.x + b.y*b.y + b.z*b.z + b.w*b.w;
    ss = wave_sum(ss);
    const float norm = sqrtf(ss);
    const float rn = 1.f / norm;
    if (lane == 0) {
        float gg = (norm - 20.f) / sqrtf(10000.f + 1e-3f) * 0.333f;
        gg = fminf(fmaxf(gg, -1.f), 1.f);
        g[row] = gg;
    }
    uint4 pk;
    pk.x = f2bf(a.x*rn) | (f2bf(a.y*rn) << 16);
    pk.y = f2bf(a.z*rn) | (f2bf(a.w*rn) << 16);
    pk.z = f2bf(b.x*rn) | (f2bf(b.y*rn) << 16);
    pk.w = f2bf(b.z*rn) | (f2bf(b.w*rn) << 16);
    *(uint4*)(ehat + (size_t)row * DDIM + lane * 8) = pk;
}

__global__ __launch_bounds__(256) void prep_wnorm(const float* __restrict__ w,
                                                  float* __restrict__ rnormw) {
    const int row  = blockIdx.x * 4 + (threadIdx.x >> 6);
    const int lane = threadIdx.x & 63;
    const float4* src = (const float4*)(w + (size_t)row * DDIM + lane * 8);
    const float4 a = src[0], b = src[1];
    float ss = a.x*a.x + a.y*a.y + a.z*a.z + a.w*a.w
             + b.x*b.x + b.y*b.y + b.z*b.z + b.w*b.w;
    ss = wave_sum(ss);
    if (lane == 0) rnormw[row] = 1.f / sqrtf(ss);
}

__global__ __launch_bounds__(256, 2) void gemm_fused_fb(
        const unsigned short* __restrict__ ehat,
        const float* __restrict__ weight,
        const float* __restrict__ rnormw,
        const int* __restrict__ labels,
        float* __restrict__ psum,
        float* __restrict__ dlab)
{
    constexpr int BM = 128, BN = 128, BK = 32;
    __shared__ __align__(16) unsigned short Asf[BM * BK];
    __shared__ __align__(16) unsigned short Bsf[BN * BK];
    __shared__ float redbuf[2][BM];

    const int bid    = blockIdx.x;
    const int tile_c = bid >> 3;
    const int tile_r = bid & 7;
    const int row0   = tile_r * BM;
    const int col0   = tile_c * BN;

    const int tid  = threadIdx.x;
    const int lane = tid & 63;
    const int wv   = tid >> 6;
    const int wr   = wv >> 1;
    const int wc   = wv & 1;

    f32x4 acc[4][4];
    #pragma unroll
    for (int m = 0; m < 4; ++m)
        #pragma unroll
        for (int n = 0; n < 4; ++n) acc[m][n] = f32x4{0.f, 0.f, 0.f, 0.f};

    const int kq    = tid & 7;
    const int brow0 = tid >> 3;
    int   cidx[4];
    float rnv[4];
    #pragma unroll
    for (int p = 0; p < 4; ++p) {
        int c = col0 + p * 32 + brow0;
        c = c < C_CLS ? c : C_CLS - 1;
        cidx[p] = c;
        rnv[p]  = rnormw[c];
    }

    for (int kt = 0; kt < DDIM / BK; ++kt) {
        const int kbase = kt * BK;
        #pragma unroll
        for (int call = 0; call < 2; ++call) {
            const int chunk = call * 256 + tid;
            const uint4 dd = *(const uint4*)(ehat + (size_t)(row0 + (chunk >> 2)) * DDIM
                                             + kbase + (chunk & 3) * 8);
            *(uint4*)(Asf + chunk * 8) = dd;
        }
        #pragma unroll
        for (int p = 0; p < 4; ++p) {
            const float4 wd = *(const float4*)(weight + (size_t)cidx[p] * DDIM + kbase + kq * 4);
            const float rr = rnv[p];
            const unsigned int lo = f2bf(wd.x * rr) | (f2bf(wd.y * rr) << 16);
            const unsigned int hi = f2bf(wd.z * rr) | (f2bf(wd.w * rr) << 16);
            *(uint2*)(Bsf + (p * 32 + brow0) * BK + kq * 4) = make_uint2(lo, hi);
        }
        __syncthreads();
        bf16x8 af[4], bfr[4];
        const int lr  = lane & 15;
        const int lko = (lane >> 4) * 8;
        #pragma unroll
        for (int m = 0; m < 4; ++m)
            af[m] = *(const bf16x8*)(Asf + (wr * 64 + m * 16 + lr) * BK + lko);
        #pragma unroll
        for (int n = 0; n < 4; ++n)
            bfr[n] = *(const bf16x8*)(Bsf + (wc * 64 + n * 16 + lr) * BK + lko);
        #pragma unroll
        for (int m = 0; m < 4; ++m)
            #pragma unroll
            for (int n = 0; n < 4; ++n)
                acc[m][n] = __builtin_amdgcn_mfma_f32_16x16x32_bf16(af[m], bfr[n], acc[m][n], 0, 0, 0);
        __syncthreads();
    }

    #pragma unroll
    for (int m = 0; m < 4; ++m) {
        #pragma unroll
        for (int j = 0; j < 4; ++j) {
            const int lrow  = wr * 64 + m * 16 + ((lane >> 4) << 2) + j;
            const int r_abs = row0 + lrow;
            const int lab   = labels[r_abs];
            float s = 0.f;
            #pragma unroll
            for (int n = 0; n < 4; ++n) {
                const int c_abs = col0 + wc * 64 + n * 16 + (lane & 15);
                float v = acc[m][n][j];
                v = fminf(fmaxf(v, -0.999f), 0.999f);
                if (c_abs == lab) dlab[r_abs] = v;
                if (c_abs < C_CLS) s += __expf(64.f * v - 64.f);
            }
            #pragma unroll
            for (int msk = 1; msk < 16; msk <<= 1) s += __shfl_xor(s, msk, 64);
            if ((lane & 15) == 0) redbuf[wc][lrow] = s;
        }
    }
    __syncthreads();
    for (int t = tid; t < BM; t += 256)
        psum[(size_t)(row0 + t) * NT_FB + tile_c] = redbuf[0][t] + redbuf[1][t];
}

__global__ __launch_bounds__(256) void reduce_rows(const float* __restrict__ psum,
                                                   const float* __restrict__ dlab,
                                                   const float* __restrict__ g,
                                                   float* __restrict__ losses, int nt) {
    const int row  = blockIdx.x * 4 + (threadIdx.x >> 6);
    const int lane = threadIdx.x & 63;
    const float* p = psum + (size_t)row * nt;
    float s = 0.f;
    for (int t = lane; t < nt; t += 64) s += p[t];
    s = wave_sum(s);
    if (lane == 0) {
        const float v  = dlab[row];
        const float gg = g[row];
        float th = acosf(v) - MARG * gg;
        th = fminf(fmaxf(th, 0.f), 3.14159265358979323846f);
        const float vm = cosf(th) - (1.f + MARG) * gg;
        s = s - __expf(64.f * v - 64.f) + __expf(64.f * vm - 64.f);
        losses[row] = 64.f + logf(s) - 64.f * vm;
    }
}

__global__ __launch_bounds__(256) void final_mean(const float* __restrict__ losses,
                                                  float* __restrict__ out) {
    const int tid = threadIdx.x;
    float s = 0.f;
    #pragma unroll
    for (int i = 0; i < 4; ++i) s += losses[tid + i * 256];
    s = wave_sum(s);
    __shared__ float red[4];
    if ((tid & 63) == 0) red[tid >> 6] = s;
    __syncthreads();
    if (tid == 0) out[0] = (red[0] + red[1] + red[2] + red[3]) * (1.f / 1024.f);
}

extern "C" void kernel_launch(void* const* d_in, const int* in_sizes, int n_in,
                              void* d_out, int out_size, void* d_ws, size_t ws_size,
                              hipStream_t stream) {
    const float* embs   = (const float*)d_in[0];
    const float* weight = (const float*)d_in[1];
    const int*   labels = (const int*)d_in[2];
    float* out = (float*)d_out;
    unsigned char* wsb = (unsigned char*)d_ws;

    // main-path layout (bytes): what8 | ehat8 | psum(float) | g | losses
    const size_t WHAT8_B = (size_t)WPAD8 * DDIM;          // 51,380,224
    const size_t EHAT8_B = (size_t)N_ROWS * DDIM;         // 524,288
    const size_t PSUM_B  = (size_t)N_ROWS * NT8 * 4;      // 3,211,264
    const size_t NEED_B  = WHAT8_B + EHAT8_B + PSUM_B + 2 * 4096;

    if (ws_size >= NEED_B) {
        unsigned char* what8 = wsb;
        unsigned char* ehat8 = wsb + WHAT8_B;
        float* psum   = (float*)(wsb + WHAT8_B + EHAT8_B);
        float* gbuf   = psum + (size_t)N_ROWS * NT8;
        float* losses = gbuf + 1024;

        prep_embs8<<<N_ROWS / 4, 256, 0, stream>>>(embs, gbuf, ehat8);
        prep_what8<<<WPAD8 / 4, 256, 0, stream>>>(weight, what8);
        gemm_s1<<<NT8 * 8, 256, 0, stream>>>(ehat8, what8, psum);
        reduce_rows8<<<N_ROWS / 4, 256, 0, stream>>>(psum, ehat8, what8, labels, gbuf, losses);
        final_mean<<<1, 256, 0, stream>>>(losses, out);
    } else {
        float* ws = (float*)d_ws;
        float* rnormw = ws + 0;
        float* gbuf   = ws + 100352;
        float* dlab   = ws + 101376;
        float* losses = ws + 102400;
        unsigned short* ehat = (unsigned short*)(ws + 103424);
        float* psum   = ws + 103424 + 262144;

        prep_embs <<<N_ROWS / 4, 256, 0, stream>>>(embs, gbuf, ehat);
        prep_wnorm<<<C_CLS / 4, 256, 0, stream>>>(weight, rnormw);
        gemm_fused_fb<<<NT_FB * 8, 256, 0, stream>>>(ehat, weight, rnormw, labels, psum, dlab);
        reduce_rows<<<N_ROWS / 4, 256, 0, stream>>>(psum, dlab, gbuf, losses, NT_FB);
        final_mean<<<1, 256, 0, stream>>>(losses, out);
    }
}